// Round 1
// baseline (1311.308 us; speedup 1.0000x reference)
//
#include <hip/hip_runtime.h>

// MultiLoRALinear: out = x @ (W + sum_n sc_n*mag_n*(up_n @ down_n))^T + b
// Strategy: fold all adapters into a single effective weight (K=512 GEMM),
// then one big bf16 MFMA GEMM (16384x4096x4096), fp32 accumulate.

#define B_DIM 4
#define S_DIM 4096
#define IND   4096
#define OUTD  4096
#define NA    8
#define RK    64
#define MROWS (B_DIM * S_DIM)   // 16384
#define KADAPT (NA * RK)        // 512

typedef __attribute__((ext_vector_type(8))) short short8;
typedef __attribute__((ext_vector_type(8))) unsigned short ushort8;
typedef __attribute__((ext_vector_type(4))) float float4v;

__device__ __forceinline__ unsigned short f2bf(float f) {
  unsigned int u = __builtin_bit_cast(unsigned int, f);
  u += 0x7FFFu + ((u >> 16) & 1u);   // round-to-nearest-even
  return (unsigned short)(u >> 16);
}

// up_eff[o, n*64+r] = bf16(ups[n,o,r] * mags[n,o] * scales[n])   (A of GEMM1, [OUTD, 512])
__global__ void fold_up_k(const float* __restrict__ ups, const float* __restrict__ mags,
                          const float* __restrict__ scales, unsigned short* __restrict__ up_eff) {
  int tid = blockIdx.x * 256 + threadIdx.x;      // 0 .. OUTD*512-1
  int o  = tid >> 9;
  int nr = tid & 511;
  int n  = nr >> 6;
  int r  = nr & 63;
  float v = ups[((size_t)n * OUTD + o) * RK + r] * mags[n * OUTD + o] * scales[n];
  up_eff[tid] = f2bf(v);
}

// dT[i, n*64+r] = bf16(downs[n,r,i])   (B^T of GEMM1, [IND, 512])
__global__ void tdown_k(const float* __restrict__ downs, unsigned short* __restrict__ dT) {
  int tid = blockIdx.x * 256 + threadIdx.x;      // 0 .. IND*512-1
  int i  = tid >> 9;
  int nr = tid & 511;
  dT[tid] = f2bf(downs[(size_t)nr * IND + i]);
}

// x -> bf16, 8 elements/thread
__global__ void cvt_x_k(const float* __restrict__ x, unsigned short* __restrict__ xb) {
  int tid = blockIdx.x * 256 + threadIdx.x;      // 0 .. MROWS*IND/8-1
  const float4v* xv = (const float4v*)x;
  float4v a = xv[2 * tid];
  float4v b = xv[2 * tid + 1];
  ushort8 o;
  o[0] = f2bf(a[0]); o[1] = f2bf(a[1]); o[2] = f2bf(a[2]); o[3] = f2bf(a[3]);
  o[4] = f2bf(b[0]); o[5] = f2bf(b[1]); o[6] = f2bf(b[2]); o[7] = f2bf(b[3]);
  ((ushort8*)xb)[tid] = o;
}

#define GLOAD_LDS16(g, l)                                                        \
  __builtin_amdgcn_global_load_lds((const __attribute__((address_space(1))) void*)(g), \
                                   (__attribute__((address_space(3))) void*)(l), 16, 0, 0)

// NT GEMM: C[m,n] = sum_k A[m,k] * B[n,k]  (A row-major [M,K], B row-major [N,K], both bf16)
// BM=BN=128, BK=32, 256 threads (4 waves), each wave computes 64x64 via 4x4 of 16x16x32 MFMA.
// EPI=0: C float = acc + extra[col] (bias).  EPI=1: C bf16 = bf16(acc + extra[row*N+col]).
template <int EPI>
__global__ __launch_bounds__(256) void gemm_nt(const unsigned short* __restrict__ A,
                                               const unsigned short* __restrict__ B,
                                               const float* __restrict__ extra,
                                               void* __restrict__ Cout,
                                               int M, int N, int K) {
  __shared__ __align__(16) unsigned short As[128 * 32];  // 8 KB
  __shared__ __align__(16) unsigned short Bs[128 * 32];  // 8 KB

  const int tid  = threadIdx.x;
  const int lane = tid & 63;
  const int w    = tid >> 6;       // wave 0..3
  const int wr   = w >> 1;         // wave row 0..1
  const int wc   = w & 1;          // wave col 0..1
  const int bm   = blockIdx.x;
  const int bn   = blockIdx.y;

  // staging decomposition: 1 KB per global_load_lds = 16 rows of 32 bf16
  const int lrow = lane >> 2;           // row within 16-row segment
  const int lk   = (lane & 3) * 8;      // k offset within 32 (0/8/16/24)

  const unsigned short* Abase = A + (size_t)(bm * 128) * K;
  const unsigned short* Bbase = B + (size_t)(bn * 128) * K;

  const int q    = lane >> 4;           // quad 0..3
  const int qr   = lane & 15;           // row(A)/col(B) within 16-tile
  const int koff = q * 8;               // k offset of this lane's fragment

  float4v acc[4][4] = {};

  for (int k0 = 0; k0 < K; k0 += 32) {
    // each wave stages 2 segments (16 rows each) of A and B
#pragma unroll
    for (int s = 0; s < 2; ++s) {
      int seg = w * 2 + s;
      int row = seg * 16 + lrow;
      GLOAD_LDS16(Abase + (size_t)row * K + k0 + lk, &As[seg * 512]);
      GLOAD_LDS16(Bbase + (size_t)row * K + k0 + lk, &Bs[seg * 512]);
    }
    __syncthreads();

    short8 af[4], bfr[4];
#pragma unroll
    for (int t = 0; t < 4; ++t) {
      int arow = wr * 64 + t * 16 + qr;
      af[t] = *(const short8*)&As[arow * 32 + koff];
      int bcol = wc * 64 + t * 16 + qr;
      bfr[t] = *(const short8*)&Bs[bcol * 32 + koff];
    }
#pragma unroll
    for (int tm = 0; tm < 4; ++tm)
#pragma unroll
      for (int tn = 0; tn < 4; ++tn)
        acc[tm][tn] = __builtin_amdgcn_mfma_f32_16x16x32_bf16(af[tm], bfr[tn], acc[tm][tn], 0, 0, 0);
    __syncthreads();
  }

  // epilogue: C/D layout col = lane&15, row = (lane>>4)*4 + reg
  if (EPI == 0) {
    float* C = (float*)Cout;
#pragma unroll
    for (int tn = 0; tn < 4; ++tn) {
      int col = bn * 128 + wc * 64 + tn * 16 + qr;
      float bias = extra[col];
#pragma unroll
      for (int tm = 0; tm < 4; ++tm) {
        int rbase = bm * 128 + wr * 64 + tm * 16 + q * 4;
#pragma unroll
        for (int r2 = 0; r2 < 4; ++r2) {
          C[(size_t)(rbase + r2) * N + col] = acc[tm][tn][r2] + bias;
        }
      }
    }
  } else {
    unsigned short* C = (unsigned short*)Cout;
#pragma unroll
    for (int tn = 0; tn < 4; ++tn) {
      int col = bn * 128 + wc * 64 + tn * 16 + qr;
#pragma unroll
      for (int tm = 0; tm < 4; ++tm) {
        int rbase = bm * 128 + wr * 64 + tm * 16 + q * 4;
#pragma unroll
        for (int r2 = 0; r2 < 4; ++r2) {
          size_t idx = (size_t)(rbase + r2) * N + col;
          C[idx] = f2bf(acc[tm][tn][r2] + extra[idx]);
        }
      }
    }
  }
}

extern "C" void kernel_launch(void* const* d_in, const int* in_sizes, int n_in,
                              void* d_out, int out_size, void* d_ws, size_t ws_size,
                              hipStream_t stream) {
  const float* x      = (const float*)d_in[0];
  const float* W      = (const float*)d_in[1];
  const float* b      = (const float*)d_in[2];
  const float* downs  = (const float*)d_in[3];
  const float* ups    = (const float*)d_in[4];
  const float* mags   = (const float*)d_in[5];
  const float* scales = (const float*)d_in[6];
  float* out = (float*)d_out;

  // workspace layout (bytes):
  //   x_bf   : MROWS*IND*2      = 134217728
  //   w_eff  : OUTD*IND*2       =  33554432
  //   up_eff : OUTD*512*2       =   4194304
  //   dT     : IND*512*2        =   4194304
  char* ws = (char*)d_ws;
  unsigned short* x_bf   = (unsigned short*)ws;
  unsigned short* w_eff  = (unsigned short*)(ws + 134217728ull);
  unsigned short* up_eff = (unsigned short*)(ws + 134217728ull + 33554432ull);
  unsigned short* dT     = (unsigned short*)(ws + 134217728ull + 33554432ull + 4194304ull);

  fold_up_k<<<dim3((OUTD * KADAPT) / 256), dim3(256), 0, stream>>>(ups, mags, scales, up_eff);
  tdown_k<<<dim3((IND * KADAPT) / 256), dim3(256), 0, stream>>>(downs, dT);
  cvt_x_k<<<dim3((MROWS * IND / 8) / 256), dim3(256), 0, stream>>>(x, x_bf);

  // W_eff = bf16(W + UpEff @ DownsT)   [OUTD, IND]
  gemm_nt<1><<<dim3(OUTD / 128, IND / 128), dim3(256), 0, stream>>>(
      up_eff, dT, W, (void*)w_eff, OUTD, IND, KADAPT);

  // out = x_bf @ W_eff^T + b   [MROWS, OUTD] fp32
  gemm_nt<0><<<dim3(MROWS / 128, OUTD / 128), dim3(256), 0, stream>>>(
      x_bf, w_eff, b, (void*)out, MROWS, OUTD, IND);
}

// Round 2
// 1298.541 us; speedup vs baseline: 1.0098x; 1.0098x over previous
//
#include <hip/hip_runtime.h>

// MultiLoRALinear: out = x @ (W + sum_n sc_n*mag_n*(up_n @ down_n))^T + b
// Strategy: fold all adapters into a single effective weight (K=512 GEMM),
// then one big bf16 MFMA GEMM (16384x4096x4096), fp32 accumulate.
// R2: XOR-swizzled LDS k-chunk placement to kill 8-way ds_read_b128 bank
// conflicts (SQ_LDS_BANK_CONFLICT 6.7e7 -> target <1.5e7).

#define B_DIM 4
#define S_DIM 4096
#define IND   4096
#define OUTD  4096
#define NA    8
#define RK    64
#define MROWS (B_DIM * S_DIM)   // 16384
#define KADAPT (NA * RK)        // 512

typedef __attribute__((ext_vector_type(8))) short short8;
typedef __attribute__((ext_vector_type(8))) unsigned short ushort8;
typedef __attribute__((ext_vector_type(4))) float float4v;

__device__ __forceinline__ unsigned short f2bf(float f) {
  unsigned int u = __builtin_bit_cast(unsigned int, f);
  u += 0x7FFFu + ((u >> 16) & 1u);   // round-to-nearest-even
  return (unsigned short)(u >> 16);
}

// up_eff[o, n*64+r] = bf16(ups[n,o,r] * mags[n,o] * scales[n])   (A of GEMM1, [OUTD, 512])
__global__ void fold_up_k(const float* __restrict__ ups, const float* __restrict__ mags,
                          const float* __restrict__ scales, unsigned short* __restrict__ up_eff) {
  int tid = blockIdx.x * 256 + threadIdx.x;      // 0 .. OUTD*512-1
  int o  = tid >> 9;
  int nr = tid & 511;
  int n  = nr >> 6;
  int r  = nr & 63;
  float v = ups[((size_t)n * OUTD + o) * RK + r] * mags[n * OUTD + o] * scales[n];
  up_eff[tid] = f2bf(v);
}

// dT[i, n*64+r] = bf16(downs[n,r,i])   (B^T of GEMM1, [IND, 512])
__global__ void tdown_k(const float* __restrict__ downs, unsigned short* __restrict__ dT) {
  int tid = blockIdx.x * 256 + threadIdx.x;      // 0 .. IND*512-1
  int i  = tid >> 9;
  int nr = tid & 511;
  dT[tid] = f2bf(downs[(size_t)nr * IND + i]);
}

// x -> bf16, 8 elements/thread
__global__ void cvt_x_k(const float* __restrict__ x, unsigned short* __restrict__ xb) {
  int tid = blockIdx.x * 256 + threadIdx.x;      // 0 .. MROWS*IND/8-1
  const float4v* xv = (const float4v*)x;
  float4v a = xv[2 * tid];
  float4v b = xv[2 * tid + 1];
  ushort8 o;
  o[0] = f2bf(a[0]); o[1] = f2bf(a[1]); o[2] = f2bf(a[2]); o[3] = f2bf(a[3]);
  o[4] = f2bf(b[0]); o[5] = f2bf(b[1]); o[6] = f2bf(b[2]); o[7] = f2bf(b[3]);
  ((ushort8*)xb)[tid] = o;
}

#define GLOAD_LDS16(g, l)                                                        \
  __builtin_amdgcn_global_load_lds((const __attribute__((address_space(1))) void*)(g), \
                                   (__attribute__((address_space(3))) void*)(l), 16, 0, 0)

// NT GEMM: C[m,n] = sum_k A[m,k] * B[n,k]  (A row-major [M,K], B row-major [N,K], both bf16)
// BM=BN=128, BK=32, 256 threads (4 waves), each wave computes 64x64 via 4x4 of 16x16x32 MFMA.
// LDS layout: slot [row][kq] (kq = 16B chunk index 0..3) holds global chunk
// kq ^ ((row>>1)&3) — spreads the 16 rows of a read-quad across all 8
// 16B-bank-positions (2-way aliasing = free) instead of 8-way conflicts.
// EPI=0: C float = acc + extra[col] (bias).  EPI=1: C bf16 = bf16(acc + extra[row*N+col]).
template <int EPI>
__global__ __launch_bounds__(256) void gemm_nt(const unsigned short* __restrict__ A,
                                               const unsigned short* __restrict__ B,
                                               const float* __restrict__ extra,
                                               void* __restrict__ Cout,
                                               int M, int N, int K) {
  __shared__ __align__(16) unsigned short As[128 * 32];  // 8 KB
  __shared__ __align__(16) unsigned short Bs[128 * 32];  // 8 KB

  const int tid  = threadIdx.x;
  const int lane = tid & 63;
  const int w    = tid >> 6;       // wave 0..3
  const int wr   = w >> 1;         // wave row 0..1
  const int wc   = w & 1;          // wave col 0..1
  const int bm   = blockIdx.x;
  const int bn   = blockIdx.y;

  // staging decomposition: 1 KB per global_load_lds = 16 rows of 32 bf16.
  // LDS dest is forced to base + lane*16; swizzle the SOURCE k-chunk so that
  // slot [lrow][kq] holds global chunk kq ^ ((lrow>>1)&3).
  const int lrow = lane >> 2;                                  // row within 16-row segment
  const int lk   = (((lane & 3) ^ ((lrow >> 1) & 3))) * 8;     // swizzled source k offset (shorts)

  const unsigned short* Abase = A + (size_t)(bm * 128) * K;
  const unsigned short* Bbase = B + (size_t)(bn * 128) * K;

  const int q    = lane >> 4;           // quad 0..3 = k-chunk wanted
  const int qr   = lane & 15;           // row(A)/col(B) within 16-tile
  // global chunk q of row r sits at LDS slot q ^ ((r>>1)&3); r ≡ qr (mod 16)
  const int ks   = (q ^ ((qr >> 1) & 3)) * 8;   // swizzled read k offset (shorts)

  float4v acc[4][4] = {};

  for (int k0 = 0; k0 < K; k0 += 32) {
    // each wave stages 2 segments (16 rows each) of A and B
#pragma unroll
    for (int s = 0; s < 2; ++s) {
      int seg = w * 2 + s;
      int row = seg * 16 + lrow;
      GLOAD_LDS16(Abase + (size_t)row * K + k0 + lk, &As[seg * 512]);
      GLOAD_LDS16(Bbase + (size_t)row * K + k0 + lk, &Bs[seg * 512]);
    }
    __syncthreads();

    short8 af[4], bfr[4];
#pragma unroll
    for (int t = 0; t < 4; ++t) {
      int arow = wr * 64 + t * 16 + qr;
      af[t] = *(const short8*)&As[arow * 32 + ks];
      int bcol = wc * 64 + t * 16 + qr;
      bfr[t] = *(const short8*)&Bs[bcol * 32 + ks];
    }
#pragma unroll
    for (int tm = 0; tm < 4; ++tm)
#pragma unroll
      for (int tn = 0; tn < 4; ++tn)
        acc[tm][tn] = __builtin_amdgcn_mfma_f32_16x16x32_bf16(af[tm], bfr[tn], acc[tm][tn], 0, 0, 0);
    __syncthreads();
  }

  // epilogue: C/D layout col = lane&15, row = (lane>>4)*4 + reg
  if (EPI == 0) {
    float* C = (float*)Cout;
#pragma unroll
    for (int tn = 0; tn < 4; ++tn) {
      int col = bn * 128 + wc * 64 + tn * 16 + qr;
      float bias = extra[col];
#pragma unroll
      for (int tm = 0; tm < 4; ++tm) {
        int rbase = bm * 128 + wr * 64 + tm * 16 + q * 4;
#pragma unroll
        for (int r2 = 0; r2 < 4; ++r2) {
          C[(size_t)(rbase + r2) * N + col] = acc[tm][tn][r2] + bias;
        }
      }
    }
  } else {
    unsigned short* C = (unsigned short*)Cout;
#pragma unroll
    for (int tn = 0; tn < 4; ++tn) {
      int col = bn * 128 + wc * 64 + tn * 16 + qr;
#pragma unroll
      for (int tm = 0; tm < 4; ++tm) {
        int rbase = bm * 128 + wr * 64 + tm * 16 + q * 4;
#pragma unroll
        for (int r2 = 0; r2 < 4; ++r2) {
          size_t idx = (size_t)(rbase + r2) * N + col;
          C[idx] = f2bf(acc[tm][tn][r2] + extra[idx]);
        }
      }
    }
  }
}

extern "C" void kernel_launch(void* const* d_in, const int* in_sizes, int n_in,
                              void* d_out, int out_size, void* d_ws, size_t ws_size,
                              hipStream_t stream) {
  const float* x      = (const float*)d_in[0];
  const float* W      = (const float*)d_in[1];
  const float* b      = (const float*)d_in[2];
  const float* downs  = (const float*)d_in[3];
  const float* ups    = (const float*)d_in[4];
  const float* mags   = (const float*)d_in[5];
  const float* scales = (const float*)d_in[6];
  float* out = (float*)d_out;

  // workspace layout (bytes):
  //   x_bf   : MROWS*IND*2      = 134217728
  //   w_eff  : OUTD*IND*2       =  33554432
  //   up_eff : OUTD*512*2       =   4194304
  //   dT     : IND*512*2        =   4194304
  char* ws = (char*)d_ws;
  unsigned short* x_bf   = (unsigned short*)ws;
  unsigned short* w_eff  = (unsigned short*)(ws + 134217728ull);
  unsigned short* up_eff = (unsigned short*)(ws + 134217728ull + 33554432ull);
  unsigned short* dT     = (unsigned short*)(ws + 134217728ull + 33554432ull + 4194304ull);

  fold_up_k<<<dim3((OUTD * KADAPT) / 256), dim3(256), 0, stream>>>(ups, mags, scales, up_eff);
  tdown_k<<<dim3((IND * KADAPT) / 256), dim3(256), 0, stream>>>(downs, dT);
  cvt_x_k<<<dim3((MROWS * IND / 8) / 256), dim3(256), 0, stream>>>(x, x_bf);

  // W_eff = bf16(W + UpEff @ DownsT)   [OUTD, IND]
  gemm_nt<1><<<dim3(OUTD / 128, IND / 128), dim3(256), 0, stream>>>(
      up_eff, dT, W, (void*)w_eff, OUTD, IND, KADAPT);

  // out = x_bf @ W_eff^T + b   [MROWS, OUTD] fp32
  gemm_nt<0><<<dim3(MROWS / 128, OUTD / 128), dim3(256), 0, stream>>>(
      x_bf, w_eff, b, (void*)out, MROWS, OUTD, IND);
}